// Round 11
// baseline (196.621 us; speedup 1.0000x reference)
//
#include <hip/hip_runtime.h>
#include <hip/hip_bf16.h>
#include <math.h>

#define EPSV 1e-5f
#define HD   128
#define WROW 24   // Wt bf16 row stride: 48B = 3 quartets, gcd(3,8)=1 -> balanced

typedef __attribute__((ext_vector_type(8))) short bf16x8;   // 8 bf16 = 4 VGPRs
typedef __attribute__((ext_vector_type(4))) float f32x4;

static __device__ __forceinline__ unsigned int bfbits(float x) {
    __hip_bfloat16 h = __float2bfloat16(x);
    unsigned short u;
    __builtin_memcpy(&u, &h, 2);
    return (unsigned int)u;
}
static __device__ __forceinline__ float bfval(float x) {
    return __bfloat162float(__float2bfloat16(x));
}

// One block per (b,t). blockDim = 256 = ND. 4 waves. Single dispatch.
// R11 vs R9 (36us kernel): the 20KB LDS feature-staging buffer (SA) is
// replaced by an in-register wave transpose. Lane L computes particle
// (wave*64+L)'s features; tile mt's A-fragment src lane is mt*16+lm (same
// wave), so 10 __shfl + quad-selects deliver the fragment directly:
//   q0 -> [H0..H3] (hi k0..7), q1 -> [H4,0,0,0] (hi k8), 
//   q2 -> [L0..L3] (lo k16..23), q3 -> [L4,0,0,0] (lo k24).
// LDS 33.5 -> ~14KB => 6-8 blocks/CU (R5->R9 showed time ~ 1/blocksPerCU).
// Numerics (verified R5-R10): 10 per-(b,t)-constant features exact fp32
// (cvec, folded into MFMA acc init); 9 varying features compensated bf16
// MFMA => exact (ahi+alo)*(whi+wlo).
__global__ __launch_bounds__(256, 6) void net_fused(
    const float* __restrict__ x0g, const float* __restrict__ xg,
    const int*   __restrict__ Ng,  const float* __restrict__ basisg,
    const float* __restrict__ vg,  const float* __restrict__ Pg,
    const float* __restrict__ W0,  const float* __restrict__ b0,
    const float* __restrict__ W1,  const float* __restrict__ b1,
    const float* __restrict__ W2,  const float* __restrict__ b2,
    float* __restrict__ out, int Tn, int NDn)
{
    __shared__ __align__(16) __hip_bfloat16 Wt1[128 * WROW];  // whi (16 used/row)
    __shared__ __align__(16) __hip_bfloat16 Wt2[128 * WROW];  // wlo
    __shared__ float cvec[HD];        // exact constant-feature contribution
    __shared__ float hvec[HD];        // pooled (atomic-accumulated) + logN
    __shared__ float h1vec[HD];       // layer-1 activations
    __shared__ float vred[4][3];      // v-mean wave partials

    const int bt   = blockIdx.x;
    const int b    = bt / Tn;
    const int tid  = threadIdx.x;
    const int lane = tid & 63;
    const int wave = tid >> 6;
    const int quad = lane >> 4;
    const int lm   = lane & 15;

    // ---- per-particle global loads (particle i = tid) ----
    const long pbase = ((long)bt * NDn + tid) * 3;
    const float xi0 = xg[pbase+0], xi1 = xg[pbase+1], xi2 = xg[pbase+2];
    const float vi0 = vg[pbase+0], vi1 = vg[pbase+1], vi2 = vg[pbase+2];

    // ---- v0 mean: wave shuffle reduce -> vred ----
    float s0 = vi0, s1 = vi1, s2 = vi2;
    #pragma unroll
    for (int off = 32; off > 0; off >>= 1) {
        s0 += __shfl_down(s0, off);
        s1 += __shfl_down(s1, off);
        s2 += __shfl_down(s2, off);
    }
    if (lane == 0) { vred[wave][0] = s0; vred[wave][1] = s1; vred[wave][2] = s2; }

    // ---- Wt staging by threads 0..127 (independent of vred; same barrier) ----
    if (tid < 128) {
        const int RV[9] = {0, 1, 2, 3, 14, 15, 16, 17, 18};
        __hip_bfloat16 r1[16], r2[16];
        #pragma unroll
        for (int kk = 0; kk < 16; ++kk) {
            r1[kk] = __float2bfloat16(0.0f);
            r2[kk] = __float2bfloat16(0.0f);
        }
        if (tid < 127) {
            #pragma unroll
            for (int kk = 0; kk < 9; ++kk) {
                const float wv = W0[RV[kk] * 127 + tid];   // coalesced across tid
                const __hip_bfloat16 hi = __float2bfloat16(wv);
                r1[kk] = hi;
                r2[kk] = __float2bfloat16(wv - __bfloat162float(hi));
            }
        }
        bf16x8* d1 = reinterpret_cast<bf16x8*>(&Wt1[tid * WROW]);
        bf16x8* d2 = reinterpret_cast<bf16x8*>(&Wt2[tid * WROW]);
        const bf16x8* s1v = reinterpret_cast<const bf16x8*>(r1);
        const bf16x8* s2v = reinterpret_cast<const bf16x8*>(r2);
        d1[0] = s1v[0]; d1[1] = s1v[1];
        d2[0] = s2v[0]; d2[1] = s2v[1];
    }
    __syncthreads();                                             // B1

    const float inv_nd = 1.0f / (float)NDn;
    const float v00 = (vred[0][0]+vred[1][0]+vred[2][0]+vred[3][0]) * inv_nd;
    const float v01 = (vred[0][1]+vred[1][1]+vred[2][1]+vred[3][1]) * inv_nd;
    const float v02 = (vred[0][2]+vred[1][2]+vred[2][2]+vred[3][2]) * inv_nd;

    // ---- per-(b,t) scalars ----
    const float p0 = x0g[bt*3+0], p1 = x0g[bt*3+1], p2 = x0g[bt*3+2];
    float bas[3][3];
    #pragma unroll
    for (int k = 0; k < 3; ++k)
        #pragma unroll
        for (int c = 0; c < 3; ++c)
            bas[k][c] = basisg[(b*3 + k)*3 + c];

    const float x0n  = sqrtf(p0*p0 + p1*p1 + p2*p2) + EPSV;
    const float ix0n = 1.0f / x0n;
    const float x0u0 = p0*ix0n, x0u1 = p1*ix0n, x0u2 = p2*ix0n;

    const float v0n  = sqrtf(v00*v00 + v01*v01 + v02*v02) + EPSV;
    const float iv0n = 1.0f / v0n;
    const float v0u0 = v00*iv0n, v0u1 = v01*iv0n, v0u2 = v02*iv0n;

    const float logN = log1pf((float)Ng[bt]);

    // ---- exact fp32 constant-feature contribution + hvec init ----
    if (tid < 128) {
        float c = 0.0f;
        if (tid < 127) {
            float fc[10];
            fc[0] = logN;
            fc[1] = x0n;
            fc[2] = x0u0*bas[0][0] + x0u1*bas[0][1] + x0u2*bas[0][2];
            fc[3] = x0u0*bas[1][0] + x0u1*bas[1][1] + x0u2*bas[1][2];
            fc[4] = x0u0*bas[2][0] + x0u1*bas[2][1] + x0u2*bas[2][2];
            fc[5] = v0n;
            fc[6] = v0u0*bas[0][0] + v0u1*bas[0][1] + v0u2*bas[0][2];
            fc[7] = v0u0*bas[1][0] + v0u1*bas[1][1] + v0u2*bas[1][2];
            fc[8] = v0u0*bas[2][0] + v0u1*bas[2][1] + v0u2*bas[2][2];
            fc[9] = x0u0*v0u0 + x0u1*v0u1 + x0u2*v0u2;
            c = b0[tid];
            #pragma unroll
            for (int i = 0; i < 10; ++i)
                c = fmaf(fc[i], W0[(4 + i) * 127 + tid], c);
        }
        cvec[tid] = c;
        hvec[tid] = (tid == 127) ? logN : 0.0f;   // atomic-accumulation base
    }

    // ---- varying features -> packed hi/lo registers (no LDS staging) ----
    unsigned int H[5], L[5];
    {
        const float xn  = sqrtf(xi0*xi0 + xi1*xi1 + xi2*xi2) + EPSV;
        const float ixn = 1.0f / xn;
        const float xu0 = xi0*ixn, xu1 = xi1*ixn, xu2 = xi2*ixn;

        const float c0 = vi0 - v00, c1 = vi1 - v01, c2 = vi2 - v02;
        const float vn  = sqrtf(c0*c0 + c1*c1 + c2*c2) + EPSV;
        const float ivn = 1.0f / vn;
        const float vu0 = c0*ivn, vu1 = c1*ivn, vu2 = c2*ivn;

        float f[9];
        f[0] = xn;                                            // W0 row 0
        f[1] = xu0*bas[0][0] + xu1*bas[0][1] + xu2*bas[0][2]; // row 1
        f[2] = xu0*bas[1][0] + xu1*bas[1][1] + xu2*bas[1][2]; // row 2
        f[3] = xu0*bas[2][0] + xu1*bas[2][1] + xu2*bas[2][2]; // row 3
        f[4] = vn;                                            // row 14
        f[5] = vu0*bas[0][0] + vu1*bas[0][1] + vu2*bas[0][2]; // row 15
        f[6] = vu0*bas[1][0] + vu1*bas[1][1] + vu2*bas[1][2]; // row 16
        f[7] = vu0*bas[2][0] + vu1*bas[2][1] + vu2*bas[2][2]; // row 17
        f[8] = xu0*vu0 + xu1*vu1 + xu2*vu2;                   // row 18

        unsigned int hb[9], lb[9];
        #pragma unroll
        for (int kk = 0; kk < 9; ++kk) {
            hb[kk] = bfbits(f[kk]);
            lb[kk] = bfbits(f[kk] - bfval(f[kk]));
        }
        #pragma unroll
        for (int j = 0; j < 4; ++j) {
            H[j] = hb[2*j] | (hb[2*j+1] << 16);
            L[j] = lb[2*j] | (lb[2*j+1] << 16);
        }
        H[4] = hb[8];
        L[4] = lb[8];
    }
    __syncthreads();                                             // B2 (cvec only)

    // ---- layer 0 MFMA: wave w owns particles [w*64, w*64+64) x 128 cols ----
    {
        const int koff = (quad & 1) * 8;    // quads 2/3 re-read same Wt data

        bf16x8 bf1[8], bf2[8];
        f32x4  cin[8];
        #pragma unroll
        for (int nt = 0; nt < 8; ++nt) {
            bf1[nt] = *reinterpret_cast<const bf16x8*>(&Wt1[(nt*16 + lm) * WROW + koff]);
            bf2[nt] = *reinterpret_cast<const bf16x8*>(&Wt2[(nt*16 + lm) * WROW + koff]);
            const float cl = cvec[nt*16 + lm];
            cin[nt] = (f32x4){cl, cl, cl, cl};   // all 4 C/D rows share column n
        }

        float pooled[8];
        #pragma unroll
        for (int nt = 0; nt < 8; ++nt) pooled[nt] = 0.0f;

        #pragma unroll
        for (int mt = 0; mt < 4; ++mt) {
            // wave transpose: pull packed features from src lane mt*16+lm
            const int src = mt*16 + lm;
            const unsigned int tH0 = (unsigned int)__shfl((int)H[0], src);
            const unsigned int tH1 = (unsigned int)__shfl((int)H[1], src);
            const unsigned int tH2 = (unsigned int)__shfl((int)H[2], src);
            const unsigned int tH3 = (unsigned int)__shfl((int)H[3], src);
            const unsigned int tH4 = (unsigned int)__shfl((int)H[4], src);
            const unsigned int tL0 = (unsigned int)__shfl((int)L[0], src);
            const unsigned int tL1 = (unsigned int)__shfl((int)L[1], src);
            const unsigned int tL2 = (unsigned int)__shfl((int)L[2], src);
            const unsigned int tL3 = (unsigned int)__shfl((int)L[3], src);
            const unsigned int tL4 = (unsigned int)__shfl((int)L[4], src);

            union { unsigned int u[4]; bf16x8 v; } a;
            a.u[0] = (quad==0) ? tH0 : (quad==1) ? tH4 : (quad==2) ? tL0 : tL4;
            a.u[1] = (quad==0) ? tH1 : (quad==2) ? tL1 : 0u;
            a.u[2] = (quad==0) ? tH2 : (quad==2) ? tL2 : 0u;
            a.u[3] = (quad==0) ? tH3 : (quad==2) ? tL3 : 0u;
            const bf16x8 af = a.v;

            #pragma unroll
            for (int nt = 0; nt < 8; ++nt) {
                f32x4 acc = __builtin_amdgcn_mfma_f32_16x16x32_bf16(af, bf1[nt], cin[nt], 0, 0, 0);
                acc = __builtin_amdgcn_mfma_f32_16x16x32_bf16(af, bf2[nt], acc, 0, 0, 0);
                #pragma unroll
                for (int r = 0; r < 4; ++r)
                    pooled[nt] += fmaxf(acc[r], 0.01f*acc[r]);   // leaky_relu
            }
        }
        #pragma unroll
        for (int nt = 0; nt < 8; ++nt) {
            pooled[nt] += __shfl_xor(pooled[nt], 16);
            pooled[nt] += __shfl_xor(pooled[nt], 32);
        }
        if (lane < 16) {
            #pragma unroll
            for (int nt = 0; nt < 8; ++nt) {
                // column 127 pools exactly 0 (zero weights, zero cvec) -> no guard
                atomicAdd(&hvec[nt*16 + lane], pooled[nt] * inv_nd);  // ds_add_f32
            }
        }
    }
    __syncthreads();                                             // B3

    // ---- layer 1: thread j full-K GEMV; W loads coalesced across j ----
    if (tid < HD) {
        float a = b1[tid];
        #pragma unroll 16
        for (int k = 0; k < HD; ++k)
            a = fmaf(hvec[k], W1[k*HD + tid], a);
        h1vec[tid] = fmaxf(a, 0.01f*a);
    }
    __syncthreads();                                             // B4

    // ---- layer 2 + output scale ----
    if (tid < HD) {
        float a = b2[tid];
        #pragma unroll 16
        for (int k = 0; k < HD; ++k)
            a = fmaf(h1vec[k], W2[k*HD + tid], a);
        out[(long)bt * HD + tid] = a / Pg[b];
    }
}

extern "C" void kernel_launch(void* const* d_in, const int* in_sizes, int n_in,
                              void* d_out, int out_size, void* d_ws, size_t ws_size,
                              hipStream_t stream) {
    const float* x0    = (const float*)d_in[0];
    const float* x     = (const float*)d_in[1];
    const int*   N     = (const int*)  d_in[2];
    const float* basis = (const float*)d_in[3];
    const float* v     = (const float*)d_in[4];
    const float* P200c = (const float*)d_in[5];
    const float* W0    = (const float*)d_in[6];
    const float* b0    = (const float*)d_in[7];
    const float* W1    = (const float*)d_in[8];
    const float* b1    = (const float*)d_in[9];
    const float* W2    = (const float*)d_in[10];
    const float* b2    = (const float*)d_in[11];
    float* out = (float*)d_out;

    const int B  = in_sizes[5];                 // P200c is [B]
    const int T  = in_sizes[2] / B;             // N is [B,T]
    const int ND = in_sizes[1] / (in_sizes[2] * 3);  // x is [B,T,ND,3]

    hipLaunchKernelGGL(net_fused, dim3(B * T), dim3(256), 0, stream,
                       x0, x, N, basis, v, P200c, W0, b0, W1, b1, W2, b2,
                       out, T, ND);
}

// Round 12
// 148.019 us; speedup vs baseline: 1.3283x; 1.3283x over previous
//
#include <hip/hip_runtime.h>
#include <hip/hip_bf16.h>
#include <math.h>

#define EPSV 1e-5f
#define HD   128
#define WROW 40   // Wt bf16 row stride: 80B = 5 quartets, gcd(5,8)=1 -> balanced

typedef __attribute__((ext_vector_type(8))) short bf16x8;   // 8 bf16 = 4 VGPRs
typedef __attribute__((ext_vector_type(4))) float f32x4;

static __device__ __forceinline__ unsigned int bfbits(float x) {
    __hip_bfloat16 h = __float2bfloat16(x);
    unsigned short u;
    __builtin_memcpy(&u, &h, 2);
    return (unsigned int)u;
}

// One block per (b,t). blockDim = 256 = ND. 4 waves. Single dispatch.
// R12 vs R9(36us)/R11(spill disaster): A-side lo compensation DROPPED --
// varying-feature bf16 rounding errors are independent across the 256 pooled
// particles (avg /16; est +1e-3 out, threshold 3.6e-2). W-side compensation
// kept for free: B rows = [whi k0..8 | wlo k16..24], A-hi duplicated in both
// k-halves => ONE mfma = ahi*(whi+wlo). 32 MFMAs/wave (was 64). Feature
// transpose in-register (5 bpermutes per tile, H[5] only) -- small enough to
// fit the launch_bounds(256,6) VGPR cap of 85 without the R11 scratch spill
// (detector: FETCH_SIZE must stay ~7MB). LDS ~11.6KB, 6 blocks/CU.
// Constant features (W0 rows 4..13) exact fp32 via cvec folded into acc init.
__global__ __launch_bounds__(256, 6) void net_fused(
    const float* __restrict__ x0g, const float* __restrict__ xg,
    const int*   __restrict__ Ng,  const float* __restrict__ basisg,
    const float* __restrict__ vg,  const float* __restrict__ Pg,
    const float* __restrict__ W0,  const float* __restrict__ b0,
    const float* __restrict__ W1,  const float* __restrict__ b1,
    const float* __restrict__ W2,  const float* __restrict__ b2,
    float* __restrict__ out, int Tn, int NDn)
{
    __shared__ __align__(16) __hip_bfloat16 Wt[128 * WROW];  // [whi|wlo] rows
    __shared__ float cvec[HD];        // exact constant-feature contribution
    __shared__ float hvec[HD];        // pooled (atomic-accumulated) + logN
    __shared__ float h1vec[HD];       // layer-1 activations
    __shared__ float vred[4][3];      // v-mean wave partials

    const int bt   = blockIdx.x;
    const int b    = bt / Tn;
    const int tid  = threadIdx.x;
    const int lane = tid & 63;
    const int wave = tid >> 6;
    const int quad = lane >> 4;
    const int lm   = lane & 15;

    // ---- per-particle global loads (particle i = tid) ----
    const long pbase = ((long)bt * NDn + tid) * 3;
    const float xi0 = xg[pbase+0], xi1 = xg[pbase+1], xi2 = xg[pbase+2];
    const float vi0 = vg[pbase+0], vi1 = vg[pbase+1], vi2 = vg[pbase+2];

    // ---- v0 mean: wave shuffle reduce -> vred ----
    float s0 = vi0, s1 = vi1, s2 = vi2;
    #pragma unroll
    for (int off = 32; off > 0; off >>= 1) {
        s0 += __shfl_down(s0, off);
        s1 += __shfl_down(s1, off);
        s2 += __shfl_down(s2, off);
    }
    if (lane == 0) { vred[wave][0] = s0; vred[wave][1] = s1; vred[wave][2] = s2; }

    // ---- Wt staging by threads 0..127: row n = [whi k0..8 | wlo k16..24] ----
    if (tid < 128) {
        const int RV[9] = {0, 1, 2, 3, 14, 15, 16, 17, 18};
        __hip_bfloat16 r1[32];
        #pragma unroll
        for (int kk = 0; kk < 32; ++kk) r1[kk] = __float2bfloat16(0.0f);
        if (tid < 127) {
            #pragma unroll
            for (int kk = 0; kk < 9; ++kk) {
                const float wv = W0[RV[kk] * 127 + tid];   // coalesced across tid
                const __hip_bfloat16 hi = __float2bfloat16(wv);
                r1[kk]      = hi;                                          // whi
                r1[16 + kk] = __float2bfloat16(wv - __bfloat162float(hi)); // wlo
            }
        }
        bf16x8* d1 = reinterpret_cast<bf16x8*>(&Wt[tid * WROW]);
        const bf16x8* s1v = reinterpret_cast<const bf16x8*>(r1);
        d1[0] = s1v[0]; d1[1] = s1v[1]; d1[2] = s1v[2]; d1[3] = s1v[3];
    }
    __syncthreads();                                             // B1

    const float inv_nd = 1.0f / (float)NDn;
    const float v00 = (vred[0][0]+vred[1][0]+vred[2][0]+vred[3][0]) * inv_nd;
    const float v01 = (vred[0][1]+vred[1][1]+vred[2][1]+vred[3][1]) * inv_nd;
    const float v02 = (vred[0][2]+vred[1][2]+vred[2][2]+vred[3][2]) * inv_nd;

    // ---- per-(b,t) scalars ----
    const float p0 = x0g[bt*3+0], p1 = x0g[bt*3+1], p2 = x0g[bt*3+2];
    float bas[3][3];
    #pragma unroll
    for (int k = 0; k < 3; ++k)
        #pragma unroll
        for (int c = 0; c < 3; ++c)
            bas[k][c] = basisg[(b*3 + k)*3 + c];

    const float x0n  = sqrtf(p0*p0 + p1*p1 + p2*p2) + EPSV;
    const float ix0n = 1.0f / x0n;
    const float x0u0 = p0*ix0n, x0u1 = p1*ix0n, x0u2 = p2*ix0n;

    const float v0n  = sqrtf(v00*v00 + v01*v01 + v02*v02) + EPSV;
    const float iv0n = 1.0f / v0n;
    const float v0u0 = v00*iv0n, v0u1 = v01*iv0n, v0u2 = v02*iv0n;

    const float logN = log1pf((float)Ng[bt]);

    // ---- exact fp32 constant-feature contribution + hvec init ----
    if (tid < 128) {
        float c = 0.0f;
        if (tid < 127) {
            float fc[10];
            fc[0] = logN;
            fc[1] = x0n;
            fc[2] = x0u0*bas[0][0] + x0u1*bas[0][1] + x0u2*bas[0][2];
            fc[3] = x0u0*bas[1][0] + x0u1*bas[1][1] + x0u2*bas[1][2];
            fc[4] = x0u0*bas[2][0] + x0u1*bas[2][1] + x0u2*bas[2][2];
            fc[5] = v0n;
            fc[6] = v0u0*bas[0][0] + v0u1*bas[0][1] + v0u2*bas[0][2];
            fc[7] = v0u0*bas[1][0] + v0u1*bas[1][1] + v0u2*bas[1][2];
            fc[8] = v0u0*bas[2][0] + v0u1*bas[2][1] + v0u2*bas[2][2];
            fc[9] = x0u0*v0u0 + x0u1*v0u1 + x0u2*v0u2;
            c = b0[tid];
            #pragma unroll
            for (int i = 0; i < 10; ++i)
                c = fmaf(fc[i], W0[(4 + i) * 127 + tid], c);
        }
        cvec[tid] = c;
        hvec[tid] = (tid == 127) ? logN : 0.0f;   // atomic-accumulation base
    }

    // ---- varying features -> packed bf16-hi registers H[5] (no LDS, no lo) ----
    unsigned int H[5];
    {
        const float xn  = sqrtf(xi0*xi0 + xi1*xi1 + xi2*xi2) + EPSV;
        const float ixn = 1.0f / xn;
        const float xu0 = xi0*ixn, xu1 = xi1*ixn, xu2 = xi2*ixn;

        const float c0 = vi0 - v00, c1 = vi1 - v01, c2 = vi2 - v02;
        const float vn  = sqrtf(c0*c0 + c1*c1 + c2*c2) + EPSV;
        const float ivn = 1.0f / vn;
        const float vu0 = c0*ivn, vu1 = c1*ivn, vu2 = c2*ivn;

        float f[9];
        f[0] = xn;                                            // W0 row 0
        f[1] = xu0*bas[0][0] + xu1*bas[0][1] + xu2*bas[0][2]; // row 1
        f[2] = xu0*bas[1][0] + xu1*bas[1][1] + xu2*bas[1][2]; // row 2
        f[3] = xu0*bas[2][0] + xu1*bas[2][1] + xu2*bas[2][2]; // row 3
        f[4] = vn;                                            // row 14
        f[5] = vu0*bas[0][0] + vu1*bas[0][1] + vu2*bas[0][2]; // row 15
        f[6] = vu0*bas[1][0] + vu1*bas[1][1] + vu2*bas[1][2]; // row 16
        f[7] = vu0*bas[2][0] + vu1*bas[2][1] + vu2*bas[2][2]; // row 17
        f[8] = xu0*vu0 + xu1*vu1 + xu2*vu2;                   // row 18

        unsigned int hb[9];
        #pragma unroll
        for (int kk = 0; kk < 9; ++kk) hb[kk] = bfbits(f[kk]);
        #pragma unroll
        for (int j = 0; j < 4; ++j) H[j] = hb[2*j] | (hb[2*j+1] << 16);
        H[4] = hb[8];
    }
    __syncthreads();                                             // B2

    // ---- layer 0 MFMA: wave w owns particles [w*64, w*64+64) x 128 cols ----
    {
        float pooled[8];
        #pragma unroll
        for (int nt = 0; nt < 8; ++nt) pooled[nt] = 0.0f;

        #pragma unroll
        for (int mt = 0; mt < 4; ++mt) {
            // wave transpose: pull packed hi-features from src lane mt*16+lm
            const int src = mt*16 + lm;
            const unsigned int t0 = (unsigned int)__shfl((int)H[0], src);
            const unsigned int t1 = (unsigned int)__shfl((int)H[1], src);
            const unsigned int t2 = (unsigned int)__shfl((int)H[2], src);
            const unsigned int t3 = (unsigned int)__shfl((int)H[3], src);
            const unsigned int t4 = (unsigned int)__shfl((int)H[4], src);

            // A-frag: even quads (k0..7 / k16..23) = f0..7; odd quads = [f8,0,0,0]
            union { unsigned int u[4]; bf16x8 v; } a;
            const bool evenq = ((quad & 1) == 0);
            a.u[0] = evenq ? t0 : t4;
            a.u[1] = evenq ? t1 : 0u;
            a.u[2] = evenq ? t2 : 0u;
            a.u[3] = evenq ? t3 : 0u;
            const bf16x8 af = a.v;

            #pragma unroll
            for (int nt = 0; nt < 8; ++nt) {
                const bf16x8 bf = *reinterpret_cast<const bf16x8*>(
                    &Wt[(nt*16 + lm) * WROW + quad*8]);
                const float cl = cvec[nt*16 + lm];
                const f32x4 cin = {cl, cl, cl, cl};
                const f32x4 acc = __builtin_amdgcn_mfma_f32_16x16x32_bf16(af, bf, cin, 0, 0, 0);
                #pragma unroll
                for (int r = 0; r < 4; ++r)
                    pooled[nt] += fmaxf(acc[r], 0.01f*acc[r]);   // leaky_relu
            }
        }
        #pragma unroll
        for (int nt = 0; nt < 8; ++nt) {
            pooled[nt] += __shfl_xor(pooled[nt], 16);
            pooled[nt] += __shfl_xor(pooled[nt], 32);
        }
        if (lane < 16) {
            #pragma unroll
            for (int nt = 0; nt < 8; ++nt) {
                // column 127: zero weights + zero cvec -> pools exactly 0
                atomicAdd(&hvec[nt*16 + lane], pooled[nt] * inv_nd);  // ds_add_f32
            }
        }
    }
    __syncthreads();                                             // B3

    // ---- layer 1: thread j full-K GEMV; W loads coalesced across j ----
    if (tid < HD) {
        float a = b1[tid];
        #pragma unroll 16
        for (int k = 0; k < HD; ++k)
            a = fmaf(hvec[k], W1[k*HD + tid], a);
        h1vec[tid] = fmaxf(a, 0.01f*a);
    }
    __syncthreads();                                             // B4

    // ---- layer 2 + output scale ----
    if (tid < HD) {
        float a = b2[tid];
        #pragma unroll 16
        for (int k = 0; k < HD; ++k)
            a = fmaf(h1vec[k], W2[k*HD + tid], a);
        out[(long)bt * HD + tid] = a / Pg[b];
    }
}

extern "C" void kernel_launch(void* const* d_in, const int* in_sizes, int n_in,
                              void* d_out, int out_size, void* d_ws, size_t ws_size,
                              hipStream_t stream) {
    const float* x0    = (const float*)d_in[0];
    const float* x     = (const float*)d_in[1];
    const int*   N     = (const int*)  d_in[2];
    const float* basis = (const float*)d_in[3];
    const float* v     = (const float*)d_in[4];
    const float* P200c = (const float*)d_in[5];
    const float* W0    = (const float*)d_in[6];
    const float* b0    = (const float*)d_in[7];
    const float* W1    = (const float*)d_in[8];
    const float* b1    = (const float*)d_in[9];
    const float* W2    = (const float*)d_in[10];
    const float* b2    = (const float*)d_in[11];
    float* out = (float*)d_out;

    const int B  = in_sizes[5];                 // P200c is [B]
    const int T  = in_sizes[2] / B;             // N is [B,T]
    const int ND = in_sizes[1] / (in_sizes[2] * 3);  // x is [B,T,ND,3]

    hipLaunchKernelGGL(net_fused, dim3(B * T), dim3(256), 0, stream,
                       x0, x, N, basis, v, P200c, W0, b0, W1, b1, W2, b2,
                       out, T, ND);
}

// Round 13
// 108.760 us; speedup vs baseline: 1.8078x; 1.3610x over previous
//
#include <hip/hip_runtime.h>
#include <hip/hip_bf16.h>
#include <math.h>

#define EPSV 1e-5f
#define HD   128
#define WROW 40   // Wt bf16 row stride: 80B = 5 quartets, gcd(5,8)=1 -> balanced

typedef __attribute__((ext_vector_type(8))) short bf16x8;   // 8 bf16 = 4 VGPRs
typedef __attribute__((ext_vector_type(4))) float f32x4;

static __device__ __forceinline__ unsigned int bfbits(float x) {
    __hip_bfloat16 h = __float2bfloat16(x);
    unsigned short u;
    __builtin_memcpy(&u, &h, 2);
    return (unsigned int)u;
}

// One block per (b,t). blockDim = 256 = ND. 4 waves. Single dispatch.
// R13 = R12 structure with __launch_bounds__(256,4). MEASURED (R11/R12 vs
// R5/R9/R10): bounds (256,6) makes the allocator clamp to 40 VGPR and spill
// the MFMA working set to scratch (FETCH 62MB/WRITE 119MB); (256,4) gives
// 64-68 VGPR, no spill. At ~64 VGPR occupancy is 8 waves/SIMD and LDS
// (12.3KB x 8 blocks = 98KB) fits -> up to 8 blocks/CU, 2x R9.
// Structure: A-side lo compensation dropped (verified free in R12: absmax
// 0.0078 == R9's) -- varying-feature bf16 noise averages out over the 256
// pooled particles. W-side compensation free: B rows [whi k0..8|wlo k16..24],
// A-hi duplicated in both halves => ONE mfma = ahi*(whi+wlo). 32 MFMAs/wave.
// Feature transpose in-register (5 shfl per tile). Constant features (W0
// rows 4..13) exact fp32 via cvec folded into acc init.
__global__ __launch_bounds__(256, 4) void net_fused(
    const float* __restrict__ x0g, const float* __restrict__ xg,
    const int*   __restrict__ Ng,  const float* __restrict__ basisg,
    const float* __restrict__ vg,  const float* __restrict__ Pg,
    const float* __restrict__ W0,  const float* __restrict__ b0,
    const float* __restrict__ W1,  const float* __restrict__ b1,
    const float* __restrict__ W2,  const float* __restrict__ b2,
    float* __restrict__ out, int Tn, int NDn)
{
    __shared__ __align__(16) __hip_bfloat16 Wt[128 * WROW];  // [whi|wlo] rows
    __shared__ float cvec[HD];        // exact constant-feature contribution
    __shared__ float hvec[HD];        // pooled (atomic-accumulated) + logN
    __shared__ float h1vec[HD];       // layer-1 activations
    __shared__ float vred[4][3];      // v-mean wave partials

    const int bt   = blockIdx.x;
    const int b    = bt / Tn;
    const int tid  = threadIdx.x;
    const int lane = tid & 63;
    const int wave = tid >> 6;
    const int quad = lane >> 4;
    const int lm   = lane & 15;

    // ---- per-particle global loads (particle i = tid) ----
    const long pbase = ((long)bt * NDn + tid) * 3;
    const float xi0 = xg[pbase+0], xi1 = xg[pbase+1], xi2 = xg[pbase+2];
    const float vi0 = vg[pbase+0], vi1 = vg[pbase+1], vi2 = vg[pbase+2];

    // ---- v0 mean: wave shuffle reduce -> vred ----
    float s0 = vi0, s1 = vi1, s2 = vi2;
    #pragma unroll
    for (int off = 32; off > 0; off >>= 1) {
        s0 += __shfl_down(s0, off);
        s1 += __shfl_down(s1, off);
        s2 += __shfl_down(s2, off);
    }
    if (lane == 0) { vred[wave][0] = s0; vred[wave][1] = s1; vred[wave][2] = s2; }

    // ---- Wt staging by threads 0..127: row n = [whi k0..8 | wlo k16..24] ----
    if (tid < 128) {
        const int RV[9] = {0, 1, 2, 3, 14, 15, 16, 17, 18};
        __hip_bfloat16 r1[32];
        #pragma unroll
        for (int kk = 0; kk < 32; ++kk) r1[kk] = __float2bfloat16(0.0f);
        if (tid < 127) {
            #pragma unroll
            for (int kk = 0; kk < 9; ++kk) {
                const float wv = W0[RV[kk] * 127 + tid];   // coalesced across tid
                const __hip_bfloat16 hi = __float2bfloat16(wv);
                r1[kk]      = hi;                                          // whi
                r1[16 + kk] = __float2bfloat16(wv - __bfloat162float(hi)); // wlo
            }
        }
        bf16x8* d1 = reinterpret_cast<bf16x8*>(&Wt[tid * WROW]);
        const bf16x8* s1v = reinterpret_cast<const bf16x8*>(r1);
        d1[0] = s1v[0]; d1[1] = s1v[1]; d1[2] = s1v[2]; d1[3] = s1v[3];
    }
    __syncthreads();                                             // B1

    const float inv_nd = 1.0f / (float)NDn;
    const float v00 = (vred[0][0]+vred[1][0]+vred[2][0]+vred[3][0]) * inv_nd;
    const float v01 = (vred[0][1]+vred[1][1]+vred[2][1]+vred[3][1]) * inv_nd;
    const float v02 = (vred[0][2]+vred[1][2]+vred[2][2]+vred[3][2]) * inv_nd;

    // ---- per-(b,t) scalars ----
    const float p0 = x0g[bt*3+0], p1 = x0g[bt*3+1], p2 = x0g[bt*3+2];
    float bas[3][3];
    #pragma unroll
    for (int k = 0; k < 3; ++k)
        #pragma unroll
        for (int c = 0; c < 3; ++c)
            bas[k][c] = basisg[(b*3 + k)*3 + c];

    const float x0n  = sqrtf(p0*p0 + p1*p1 + p2*p2) + EPSV;
    const float ix0n = 1.0f / x0n;
    const float x0u0 = p0*ix0n, x0u1 = p1*ix0n, x0u2 = p2*ix0n;

    const float v0n  = sqrtf(v00*v00 + v01*v01 + v02*v02) + EPSV;
    const float iv0n = 1.0f / v0n;
    const float v0u0 = v00*iv0n, v0u1 = v01*iv0n, v0u2 = v02*iv0n;

    const float logN = log1pf((float)Ng[bt]);

    // ---- exact fp32 constant-feature contribution + hvec init ----
    if (tid < 128) {
        float c = 0.0f;
        if (tid < 127) {
            float fc[10];
            fc[0] = logN;
            fc[1] = x0n;
            fc[2] = x0u0*bas[0][0] + x0u1*bas[0][1] + x0u2*bas[0][2];
            fc[3] = x0u0*bas[1][0] + x0u1*bas[1][1] + x0u2*bas[1][2];
            fc[4] = x0u0*bas[2][0] + x0u1*bas[2][1] + x0u2*bas[2][2];
            fc[5] = v0n;
            fc[6] = v0u0*bas[0][0] + v0u1*bas[0][1] + v0u2*bas[0][2];
            fc[7] = v0u0*bas[1][0] + v0u1*bas[1][1] + v0u2*bas[1][2];
            fc[8] = v0u0*bas[2][0] + v0u1*bas[2][1] + v0u2*bas[2][2];
            fc[9] = x0u0*v0u0 + x0u1*v0u1 + x0u2*v0u2;
            c = b0[tid];
            #pragma unroll
            for (int i = 0; i < 10; ++i)
                c = fmaf(fc[i], W0[(4 + i) * 127 + tid], c);
        }
        cvec[tid] = c;
        hvec[tid] = (tid == 127) ? logN : 0.0f;   // atomic-accumulation base
    }

    // ---- varying features -> packed bf16-hi registers H[5] (no LDS, no lo) ----
    unsigned int H[5];
    {
        const float xn  = sqrtf(xi0*xi0 + xi1*xi1 + xi2*xi2) + EPSV;
        const float ixn = 1.0f / xn;
        const float xu0 = xi0*ixn, xu1 = xi1*ixn, xu2 = xi2*ixn;

        const float c0 = vi0 - v00, c1 = vi1 - v01, c2 = vi2 - v02;
        const float vn  = sqrtf(c0*c0 + c1*c1 + c2*c2) + EPSV;
        const float ivn = 1.0f / vn;
        const float vu0 = c0*ivn, vu1 = c1*ivn, vu2 = c2*ivn;

        float f[9];
        f[0] = xn;                                            // W0 row 0
        f[1] = xu0*bas[0][0] + xu1*bas[0][1] + xu2*bas[0][2]; // row 1
        f[2] = xu0*bas[1][0] + xu1*bas[1][1] + xu2*bas[1][2]; // row 2
        f[3] = xu0*bas[2][0] + xu1*bas[2][1] + xu2*bas[2][2]; // row 3
        f[4] = vn;                                            // row 14
        f[5] = vu0*bas[0][0] + vu1*bas[0][1] + vu2*bas[0][2]; // row 15
        f[6] = vu0*bas[1][0] + vu1*bas[1][1] + vu2*bas[1][2]; // row 16
        f[7] = vu0*bas[2][0] + vu1*bas[2][1] + vu2*bas[2][2]; // row 17
        f[8] = xu0*vu0 + xu1*vu1 + xu2*vu2;                   // row 18

        unsigned int hb[9];
        #pragma unroll
        for (int kk = 0; kk < 9; ++kk) hb[kk] = bfbits(f[kk]);
        #pragma unroll
        for (int j = 0; j < 4; ++j) H[j] = hb[2*j] | (hb[2*j+1] << 16);
        H[4] = hb[8];
    }
    __syncthreads();                                             // B2

    // ---- layer 0 MFMA: wave w owns particles [w*64, w*64+64) x 128 cols ----
    {
        float pooled[8];
        #pragma unroll
        for (int nt = 0; nt < 8; ++nt) pooled[nt] = 0.0f;

        #pragma unroll
        for (int mt = 0; mt < 4; ++mt) {
            // wave transpose: pull packed hi-features from src lane mt*16+lm
            const int src = mt*16 + lm;
            const unsigned int t0 = (unsigned int)__shfl((int)H[0], src);
            const unsigned int t1 = (unsigned int)__shfl((int)H[1], src);
            const unsigned int t2 = (unsigned int)__shfl((int)H[2], src);
            const unsigned int t3 = (unsigned int)__shfl((int)H[3], src);
            const unsigned int t4 = (unsigned int)__shfl((int)H[4], src);

            // A-frag: even quads (k0..7 / k16..23) = f0..7; odd quads = [f8,0,0,0]
            union { unsigned int u[4]; bf16x8 v; } a;
            const bool evenq = ((quad & 1) == 0);
            a.u[0] = evenq ? t0 : t4;
            a.u[1] = evenq ? t1 : 0u;
            a.u[2] = evenq ? t2 : 0u;
            a.u[3] = evenq ? t3 : 0u;
            const bf16x8 af = a.v;

            #pragma unroll
            for (int nt = 0; nt < 8; ++nt) {
                const bf16x8 bf = *reinterpret_cast<const bf16x8*>(
                    &Wt[(nt*16 + lm) * WROW + quad*8]);
                const float cl = cvec[nt*16 + lm];
                const f32x4 cin = {cl, cl, cl, cl};
                const f32x4 acc = __builtin_amdgcn_mfma_f32_16x16x32_bf16(af, bf, cin, 0, 0, 0);
                #pragma unroll
                for (int r = 0; r < 4; ++r)
                    pooled[nt] += fmaxf(acc[r], 0.01f*acc[r]);   // leaky_relu
            }
        }
        #pragma unroll
        for (int nt = 0; nt < 8; ++nt) {
            pooled[nt] += __shfl_xor(pooled[nt], 16);
            pooled[nt] += __shfl_xor(pooled[nt], 32);
        }
        if (lane < 16) {
            #pragma unroll
            for (int nt = 0; nt < 8; ++nt) {
                // column 127: zero weights + zero cvec -> pools exactly 0
                atomicAdd(&hvec[nt*16 + lane], pooled[nt] * inv_nd);  // ds_add_f32
            }
        }
    }
    __syncthreads();                                             // B3

    // ---- layer 1: thread j full-K GEMV; W loads coalesced across j ----
    if (tid < HD) {
        float a = b1[tid];
        #pragma unroll 16
        for (int k = 0; k < HD; ++k)
            a = fmaf(hvec[k], W1[k*HD + tid], a);
        h1vec[tid] = fmaxf(a, 0.01f*a);
    }
    __syncthreads();                                             // B4

    // ---- layer 2 + output scale ----
    if (tid < HD) {
        float a = b2[tid];
        #pragma unroll 16
        for (int k = 0; k < HD; ++k)
            a = fmaf(h1vec[k], W2[k*HD + tid], a);
        out[(long)bt * HD + tid] = a / Pg[b];
    }
}

extern "C" void kernel_launch(void* const* d_in, const int* in_sizes, int n_in,
                              void* d_out, int out_size, void* d_ws, size_t ws_size,
                              hipStream_t stream) {
    const float* x0    = (const float*)d_in[0];
    const float* x     = (const float*)d_in[1];
    const int*   N     = (const int*)  d_in[2];
    const float* basis = (const float*)d_in[3];
    const float* v     = (const float*)d_in[4];
    const float* P200c = (const float*)d_in[5];
    const float* W0    = (const float*)d_in[6];
    const float* b0    = (const float*)d_in[7];
    const float* W1    = (const float*)d_in[8];
    const float* b1    = (const float*)d_in[9];
    const float* W2    = (const float*)d_in[10];
    const float* b2    = (const float*)d_in[11];
    float* out = (float*)d_out;

    const int B  = in_sizes[5];                 // P200c is [B]
    const int T  = in_sizes[2] / B;             // N is [B,T]
    const int ND = in_sizes[1] / (in_sizes[2] * 3);  // x is [B,T,ND,3]

    hipLaunchKernelGGL(net_fused, dim3(B * T), dim3(256), 0, stream,
                       x0, x, N, basis, v, P200c, W0, b0, W1, b1, W2, b2,
                       out, T, ND);
}